// Round 6
// baseline (203.251 us; speedup 1.0000x reference)
//
#include <hip/hip_runtime.h>
#include <hip/hip_bf16.h>

#define B_ 4
#define S_ 2048
#define D_ 512
#define H_ 8
#define A_ 64

typedef __attribute__((ext_vector_type(8))) __bf16 bf16x8;
typedef __attribute__((ext_vector_type(4))) __bf16 bf16x4;
typedef __attribute__((ext_vector_type(4))) float f32x4;

static __device__ __forceinline__ f32x4 mfma16(bf16x8 a, bf16x8 b, f32x4 c) {
  return __builtin_amdgcn_mfma_f32_16x16x32_bf16(a, b, c, 0, 0, 0);
}

static __device__ __forceinline__ f32x4 zero4() {
  f32x4 z = {0.f, 0.f, 0.f, 0.f};
  return z;
}

// 0.125 (1/sqrt(A)) * log2(e): scores are consumed by v_exp (2^x) in flash_kernel
#define QSCALE 0.18033688011f

#if __has_builtin(__builtin_amdgcn_exp2f)
#define EXP2(x) __builtin_amdgcn_exp2f(x)
#else
#define EXP2(x) exp2f(x)
#endif

// async global->LDS, 16B per lane, lds dest = wave-uniform base + lane*16
#define GLDS(g, l)                                                      \
  __builtin_amdgcn_global_load_lds(                                     \
      (const __attribute__((address_space(1))) void*)(g),               \
      (__attribute__((address_space(3))) void*)(l), 16, 0, 0)

// ------------- merged input prep: fp32->bf16 activations + LDS-transposed weights -------------
__global__ void prep_all_kernel(const float* __restrict__ q, const float* __restrict__ k,
                                const float* __restrict__ v,
                                const float* __restrict__ Wq, const float* __restrict__ Wk,
                                const float* __restrict__ Wv, const float* __restrict__ Wo,
                                __bf16* __restrict__ xq, __bf16* __restrict__ xk,
                                __bf16* __restrict__ xv,
                                __bf16* __restrict__ tq, __bf16* __restrict__ tk,
                                __bf16* __restrict__ tv, __bf16* __restrict__ to_,
                                int* __restrict__ tickets) {
  __shared__ float tile[64][65];
  // reset flash's per-XCD ticket counters each replay (runs before flash in-stream)
  if (blockIdx.x == 0 && threadIdx.x < 8) tickets[threadIdx.x] = 0;
  if (blockIdx.x < 12288) {
    int idx = blockIdx.x * 256 + threadIdx.x;  // 3 * 2^20 threads, one float4 each
    int which = idx >> 20;
    int i = idx & ((1 << 20) - 1);
    const float4* s = (const float4*)(which == 0 ? q : (which == 1 ? k : v));
    __bf16* d = (which == 0) ? xq : (which == 1 ? xk : xv);
    float4 f = s[i];
    bf16x4 o;
    o.x = (__bf16)f.x; o.y = (__bf16)f.y; o.z = (__bf16)f.z; o.w = (__bf16)f.w;
    *(bf16x4*)(d + 4 * i) = o;
  } else {
    int t = blockIdx.x - 12288;   // 0..255
    if (t < 192) {
      // Wq/Wk/Wv: tq[n=h*64+a][k=d] = W[h][d][a] (coalesced both sides via LDS transpose)
      int mat = t >> 6;
      int h = (t >> 3) & 7;
      int d0 = (t & 7) * 64;
      const float* W = (mat == 0) ? Wq : (mat == 1 ? Wk : Wv);
      __bf16* dst = (mat == 0) ? tq : (mat == 1 ? tk : tv);
      float sc = (mat == 0) ? QSCALE : 1.0f;   // fold 1/sqrt(A)*log2e into Q projection
      int a = threadIdx.x & 63, r0 = threadIdx.x >> 6;
#pragma unroll
      for (int i = 0; i < 16; i++) {
        int dd = r0 * 16 + i;
        tile[dd][a] = W[(h * D_ + d0 + dd) * A_ + a] * sc;
      }
      __syncthreads();
      int dd = threadIdx.x & 63, a0 = threadIdx.x >> 6;
#pragma unroll
      for (int i = 0; i < 16; i++) {
        int a2 = a0 * 16 + i;
        dst[(h * 64 + a2) * D_ + d0 + dd] = (__bf16)tile[dd][a2];
      }
    } else {
      // Wo: Wot[n=d][k=f] = Wo[f][d]
      int t2 = t - 192;           // 0..63
      int f0 = (t2 >> 3) * 64, d0 = (t2 & 7) * 64;
      int d = threadIdx.x & 63, r0 = threadIdx.x >> 6;
#pragma unroll
      for (int i = 0; i < 16; i++) {
        int ff = r0 * 16 + i;
        tile[ff][d] = Wo[(f0 + ff) * D_ + d0 + d];
      }
      __syncthreads();
      int f = threadIdx.x & 63, a0 = threadIdx.x >> 6;
#pragma unroll
      for (int i = 0; i < 16; i++) {
        int dd = a0 * 16 + i;
        to_[(d0 + dd) * D_ + f0 + f] = (__bf16)tile[f][dd];
      }
    }
  }
}

// ---------------- QKV projection GEMM: [8192x512] @ [512x512] per matrix ----------------
// 128x128 tile, 4 waves 2x2, BK=64, double-buffered global_load_lds staging (16B-granule XOR
// swizzle on both sides). Round-4 verified.
__global__ __launch_bounds__(256) void proj_gemm_kernel(
    const __bf16* __restrict__ Xq, const __bf16* __restrict__ Xk, const __bf16* __restrict__ Xv,
    const __bf16* __restrict__ Wtq, const __bf16* __restrict__ Wtk, const __bf16* __restrict__ Wtv,
    const float* __restrict__ bq, const float* __restrict__ bk, const float* __restrict__ bv,
    __bf16* __restrict__ Qb, __bf16* __restrict__ Kb, __bf16* __restrict__ Vtb) {
  int z = blockIdx.z;
  const __bf16* X  = (z == 0) ? Xq  : (z == 1 ? Xk  : Xv);
  const __bf16* Wt = (z == 0) ? Wtq : (z == 1 ? Wtk : Wtv);
  const float* bias = (z == 0) ? bq : (z == 1 ? bk : bv);
  float bscale = (z == 0) ? QSCALE : 1.0f;

  int lane = threadIdx.x & 63, wv = threadIdx.x >> 6;
  int wr = wv >> 1, wc = wv & 1;
  int quad = lane >> 4, lc = lane & 15;
  int M0 = blockIdx.x * 128, N0 = blockIdx.y * 128;
  int m0 = M0 + wr * 64, n0 = N0 + wc * 64;

  // 64 KiB: [buf][A|B][128][64]; epilogue staging aliases this after the loop
  __shared__ __align__(16) __bf16 smem[2 * 2 * 128 * 64];
#define AB(buf) (smem + (buf) * 16384)
#define BB(buf) (smem + (buf) * 16384 + 8192)

  int srow = lane >> 3;                 // 0..7
  int sg = ((lane & 7) ^ srow) * 8;     // pre-swizzled source granule

  // prologue: stage K-step 0 into buf 0
#pragma unroll
  for (int i = 0; i < 4; ++i) {
    int r0 = wv * 32 + i * 8;
    GLDS(X  + (M0 + r0 + srow) * D_ + sg, AB(0) + r0 * 64);
    GLDS(Wt + (N0 + r0 + srow) * D_ + sg, BB(0) + r0 * 64);
  }

  f32x4 acc[4][4];
#pragma unroll
  for (int mt = 0; mt < 4; mt++)
#pragma unroll
    for (int nt = 0; nt < 4; nt++) acc[mt][nt] = zero4();

  __syncthreads();   // drains vmcnt(0): step-0 tiles staged & visible

  for (int j = 0; j < 8; ++j) {
    int cb = j & 1;
    if (j < 7) {
      int k0 = (j + 1) * 64;
#pragma unroll
      for (int i = 0; i < 4; ++i) {
        int r0 = wv * 32 + i * 8;
        GLDS(X  + (M0 + r0 + srow) * D_ + k0 + sg, AB(cb ^ 1) + r0 * 64);
        GLDS(Wt + (N0 + r0 + srow) * D_ + k0 + sg, BB(cb ^ 1) + r0 * 64);
      }
    }
    const __bf16* Al = AB(cb);
    const __bf16* Bl = BB(cb);
#pragma unroll
    for (int kk = 0; kk < 2; ++kk) {
      int gp = ((kk * 4 + quad) ^ (lc & 7)) * 8;
      bf16x8 a[4], bb[4];
#pragma unroll
      for (int mt = 0; mt < 4; mt++)
        a[mt] = *(const bf16x8*)(Al + (wr * 64 + mt * 16 + lc) * 64 + gp);
#pragma unroll
      for (int nt = 0; nt < 4; nt++)
        bb[nt] = *(const bf16x8*)(Bl + (wc * 64 + nt * 16 + lc) * 64 + gp);
#pragma unroll
      for (int mt = 0; mt < 4; mt++)
#pragma unroll
        for (int nt = 0; nt < 4; nt++)
          acc[mt][nt] = mfma16(a[mt], bb[nt], acc[mt][nt]);
    }
    __syncthreads();   // all waves done reading buf cb; next tile staged & visible
  }

  // epilogue staging aliases smem (all waves are past the loop's final barrier)
  __bf16* vlds = smem + wv * (64 * 72);

  int h = n0 >> 6;                 // one head per wave tile
  int b = m0 >> 11, s0 = m0 & (S_ - 1);
  if (z < 2) {
    // stage row-major [s-row][a-col], then 128B-contiguous row stores
#pragma unroll
    for (int nt = 0; nt < 4; nt++) {
      int col = n0 + nt * 16 + lc;
      float bval = bias[col] * bscale;
#pragma unroll
      for (int mt = 0; mt < 4; mt++)
#pragma unroll
        for (int r = 0; r < 4; r++)
          vlds[(mt * 16 + quad * 4 + r) * 72 + nt * 16 + lc] = (__bf16)(acc[mt][nt][r] + bval);
    }
    __asm__ volatile("s_waitcnt lgkmcnt(0)" ::: "memory");
    __bf16* dst = (z == 0) ? Qb : Kb;
#pragma unroll
    for (int it = 0; it < 8; it++) {
      int row = it * 8 + (lane >> 3);
      int c8 = (lane & 7) * 8;
      bf16x8 vv = *(const bf16x8*)(vlds + row * 72 + c8);
      *(bf16x8*)(dst + ((b * H_ + h) * S_ + s0 + row) * A_ + c8) = vv;   // [B,H,S,A]
    }
  } else {
    // V: stage transposed [a-row][s-col] (packed b64 writes), coalesced [B,H,A,S] stores
#pragma unroll
    for (int nt = 0; nt < 4; nt++) {
      int col = n0 + nt * 16 + lc;
      float bval = bias[col];
#pragma unroll
      for (int mt = 0; mt < 4; mt++) {
        bf16x4 pk;
#pragma unroll
        for (int r = 0; r < 4; r++) pk[r] = (__bf16)(acc[mt][nt][r] + bval);
        *(bf16x4*)(vlds + (nt * 16 + lc) * 72 + mt * 16 + quad * 4) = pk;
      }
    }
    __asm__ volatile("s_waitcnt lgkmcnt(0)" ::: "memory");
#pragma unroll
    for (int it = 0; it < 8; it++) {
      int a_l = it * 8 + (lane >> 3);
      int s_l = (lane & 7) * 8;
      bf16x8 vvv = *(const bf16x8*)(vlds + a_l * 72 + s_l);
      *(bf16x8*)(Vtb + ((b * H_ + h) * A_ + a_l) * S_ + s0 + s_l) = vvv;
    }
  }
}

// ---------------- flash attention: shared-KV LDS + per-XCD ticket work queue ----------------
// 512 blocks, 2/CU. Work unit = (bh_local 0..3, beta 0..15), 64 units per XCD.
// Each block pulls a ticket from its XCD's atomic counter (blockIdx&7 -> XCD keeps the round-3
// L2 pinning that measured 12MB FETCH). Units sorted longest-first: ticket t<32 -> rank=t
// (betas 0..7), t>=32 -> rank=95-t (betas 15..8 reversed). Any dispatch where every CU starts
// its 1st block before any CU starts its 2nd gives each CU ranks (e, 63-e) -> betas (b, 15-b)
// -> 34 tiles per CU, regardless of the CU-slot map (round-5's static pairing assumed a map
// that proved wrong: only +9%). Mapping is a bijection -> correctness is dispatch-independent.
// beta==15 blocks also perform the fused row-2047 fix (O = mean(V)).
__global__ __launch_bounds__(256, 4) void flash_kernel(const __bf16* __restrict__ Q,
                                                       const __bf16* __restrict__ K,
                                                       const __bf16* __restrict__ Vt,
                                                       __bf16* __restrict__ O,
                                                       int* __restrict__ tickets) {
  int xcd = blockIdx.x & 7;
  __shared__ int s_ticket;
  if (threadIdx.x == 0) s_ticket = atomicAdd(&tickets[xcd], 1);
  __syncthreads();
  int tk = s_ticket & 63;
  int rank = (tk < 32) ? tk : 95 - tk;
  int beta = rank >> 2;                   // q-group 0..15
  int bh = xcd * 4 + (rank & 3);          // 4 bh per XCD: K+V L2-resident
  int lane = threadIdx.x & 63, wv = threadIdx.x >> 6;
  int quad = lane >> 4, lc = lane & 15;
  int R0 = beta * 128 + wv * 32;          // this wave's first q-row
  int ntile = 32 - 2 * beta;              // key tiles t0..31
  int t0 = 2 * beta;

  const __bf16* Qp = Q + bh * S_ * A_;   // [S][64]
  const __bf16* Kp = K + bh * S_ * A_;   // [S][64]
  const __bf16* Vp = Vt + bh * A_ * S_;  // [64][S]

  __shared__ __align__(16) __bf16 kvbuf[2][2][64][64];   // [buf][0=K,1=V][row][64] = 32 KiB
  __shared__ __align__(16) __bf16 plds_all[4][32][72];   // per-wave P / epilogue staging
  __bf16* plds = &plds_all[wv][0][0];

  int srow = lane >> 3;                                  // 0..7
  int sg = ((lane & 7) ^ srow) * 8;                      // swizzled source elem offset

  // ---- prologue: stage tile t0 into buf0; Q fragment loads overlap ----
  {
    int kt = t0 << 6;
#pragma unroll
    for (int i = 0; i < 2; ++i) {
      int r0 = wv * 16 + i * 8;
      GLDS(Kp + (kt + r0 + srow) * A_ + sg, &kvbuf[0][0][r0][0]);
      GLDS(Vp + (r0 + srow) * S_ + kt + sg, &kvbuf[0][1][r0][0]);
    }
  }

  bf16x8 qf[2][2];
#pragma unroll
  for (int qt = 0; qt < 2; qt++) {
    qf[qt][0] = *(const bf16x8*)(Qp + (R0 + qt * 16 + lc) * A_ + quad * 8);
    qf[qt][1] = *(const bf16x8*)(Qp + (R0 + qt * 16 + lc) * A_ + 32 + quad * 8);
  }

  f32x4 o[2][4];
  float lsum[2][4];
#pragma unroll
  for (int qt = 0; qt < 2; qt++)
#pragma unroll
    for (int t = 0; t < 4; t++) { o[qt][t] = zero4(); lsum[qt][t] = 0.f; }

  int g0 = (quad ^ (lc & 7)) * 8;         // swizzled granule offsets for frag reads
  int g1 = ((quad + 4) ^ (lc & 7)) * 8;

  __syncthreads();   // drains vmcnt(0): tile t0 staged & visible

  for (int j = 0; j < ntile; ++j) {
    int t = t0 + j;
    int cb = j & 1;
    if (j + 1 < ntile) {
      int ktn = (t + 1) << 6;
#pragma unroll
      for (int i = 0; i < 2; ++i) {
        int r0 = wv * 16 + i * 8;
        GLDS(Kp + (ktn + r0 + srow) * A_ + sg, &kvbuf[cb ^ 1][0][r0][0]);
        GLDS(Vp + (r0 + srow) * S_ + ktn + sg, &kvbuf[cb ^ 1][1][r0][0]);
      }
    }
    bool skip = (t * 64 + 63 <= R0);
    if (!skip) {
      const __bf16* Kl = &kvbuf[cb][0][0][0];
      const __bf16* Vl = &kvbuf[cb][1][0][0];
      f32x4 sc[2][4];
#pragma unroll
      for (int nt = 0; nt < 4; nt++) {
        int rr = nt * 16 + lc;
        bf16x8 kf0 = *(const bf16x8*)(Kl + rr * 64 + g0);
        bf16x8 kf1 = *(const bf16x8*)(Kl + rr * 64 + g1);
#pragma unroll
        for (int qt = 0; qt < 2; qt++) {
          f32x4 ss = zero4();
          ss = mfma16(qf[qt][0], kf0, ss);
          ss = mfma16(qf[qt][1], kf1, ss);
          sc[qt][nt] = ss;
        }
      }
      if (t * 64 < R0 + 32) {
#pragma unroll
        for (int qt = 0; qt < 2; qt++)
#pragma unroll
          for (int nt = 0; nt < 4; nt++) {
            int col = t * 64 + nt * 16 + lc;
#pragma unroll
            for (int r = 0; r < 4; r++) {
              int row = R0 + qt * 16 + quad * 4 + r;
              float pv = (col <= row) ? 0.0f : EXP2(sc[qt][nt][r]);
              lsum[qt][r] += pv;
              plds[(qt * 16 + quad * 4 + r) * 72 + nt * 16 + lc] = (__bf16)pv;
            }
          }
      } else {
#pragma unroll
        for (int qt = 0; qt < 2; qt++)
#pragma unroll
          for (int nt = 0; nt < 4; nt++)
#pragma unroll
            for (int r = 0; r < 4; r++) {
              float pv = EXP2(sc[qt][nt][r]);
              lsum[qt][r] += pv;
              plds[(qt * 16 + quad * 4 + r) * 72 + nt * 16 + lc] = (__bf16)pv;
            }
      }
      __asm__ volatile("s_waitcnt lgkmcnt(0)" ::: "memory");
      bf16x8 pf[2][2];
#pragma unroll
      for (int qt = 0; qt < 2; qt++) {
        pf[qt][0] = *(const bf16x8*)(plds + (qt * 16 + lc) * 72 + quad * 8);
        pf[qt][1] = *(const bf16x8*)(plds + (qt * 16 + lc) * 72 + 32 + quad * 8);
      }
      __builtin_amdgcn_s_setprio(1);
#pragma unroll
      for (int ot = 0; ot < 4; ot++) {
        int rr = ot * 16 + lc;
        bf16x8 vf0 = *(const bf16x8*)(Vl + rr * 64 + g0);
        bf16x8 vf1 = *(const bf16x8*)(Vl + rr * 64 + g1);
#pragma unroll
        for (int qt = 0; qt < 2; qt++) {
          o[qt][ot] = mfma16(pf[qt][0], vf0, o[qt][ot]);
          o[qt][ot] = mfma16(pf[qt][1], vf1, o[qt][ot]);
        }
      }
      __builtin_amdgcn_s_setprio(0);
    }
    __syncthreads();
  }

#pragma unroll
  for (int qt = 0; qt < 2; qt++)
#pragma unroll
    for (int r = 0; r < 4; r++) {
      float l = lsum[qt][r];
#pragma unroll
      for (int off = 1; off < 16; off <<= 1) l += __shfl_xor(l, off, 64);
      lsum[qt][r] = l;
    }

#pragma unroll
  for (int qt = 0; qt < 2; qt++)
#pragma unroll
    for (int r = 0; r < 4; r++) {
      float rl = 1.0f / lsum[qt][r];
#pragma unroll
      for (int ot = 0; ot < 4; ot++)
        plds[(qt * 16 + quad * 4 + r) * 72 + ot * 16 + lc] = (__bf16)(o[qt][ot][r] * rl);
    }
  __asm__ volatile("s_waitcnt lgkmcnt(0)" ::: "memory");
  int b = bh >> 3, h = bh & 7;
#pragma unroll
  for (int it = 0; it < 4; it++) {
    int row = it * 8 + (lane >> 3);
    int c8 = (lane & 7) * 8;
    int grow = R0 + row;
    if (grow != S_ - 1)
      *(bf16x8*)(O + (b * S_ + grow) * (H_ * A_) + h * 64 + c8) =
          *(const bf16x8*)(plds + row * 72 + c8);
  }

  // ---- fused row-2047 fix: softmax over all -1e9 is uniform -> O = mean(V) ----
  if (beta == 15) {
    int a = threadIdx.x >> 2;       // 0..63
    int li = threadIdx.x & 3;       // 4 lanes per a-row
    const __bf16* src = Vp + a * S_;
    float ssum = 0.f;
#pragma unroll 8
    for (int j2 = 0; j2 < 64; j2++) {
      bf16x8 vv = *(const bf16x8*)(src + (j2 * 4 + li) * 8);
#pragma unroll
      for (int e = 0; e < 8; e++) ssum += (float)vv[e];
    }
    ssum += __shfl_xor(ssum, 1, 64);
    ssum += __shfl_xor(ssum, 2, 64);
    if (li == 0)
      O[(b * S_ + (S_ - 1)) * (H_ * A_) + h * 64 + a] = (__bf16)(ssum * (1.0f / 2048.0f));
  }
}

// ---------------- output projection: [8192x512] @ [512x512] + bo, fp32 out ----------------
// Same LDS-staged BK=64 double-buffered main loop as proj_gemm; direct fp32 epilogue stores.
__global__ __launch_bounds__(256) void out_gemm_kernel(const __bf16* __restrict__ Ob,
                                                       const __bf16* __restrict__ Wot,
                                                       const float* __restrict__ bo,
                                                       float* __restrict__ out) {
  int lane = threadIdx.x & 63, wv = threadIdx.x >> 6;
  int wr = wv >> 1, wc = wv & 1;
  int quad = lane >> 4, lc = lane & 15;
  int M0 = blockIdx.x * 128, N0 = blockIdx.y * 128;
  int m0 = M0 + wr * 64, n0 = N0 + wc * 64;

  __shared__ __align__(16) __bf16 smem[2 * 2 * 128 * 64];

  int srow = lane >> 3;
  int sg = ((lane & 7) ^ srow) * 8;

#pragma unroll
  for (int i = 0; i < 4; ++i) {
    int r0 = wv * 32 + i * 8;
    GLDS(Ob  + (M0 + r0 + srow) * D_ + sg, AB(0) + r0 * 64);
    GLDS(Wot + (N0 + r0 + srow) * D_ + sg, BB(0) + r0 * 64);
  }

  f32x4 acc[4][4];
#pragma unroll
  for (int mt = 0; mt < 4; mt++)
#pragma unroll
    for (int nt = 0; nt < 4; nt++) acc[mt][nt] = zero4();

  __syncthreads();

  for (int j = 0; j < 8; ++j) {
    int cb = j & 1;
    if (j < 7) {
      int k0 = (j + 1) * 64;
#pragma unroll
      for (int i = 0; i < 4; ++i) {
        int r0 = wv * 32 + i * 8;
        GLDS(Ob  + (M0 + r0 + srow) * D_ + k0 + sg, AB(cb ^ 1) + r0 * 64);
        GLDS(Wot + (N0 + r0 + srow) * D_ + k0 + sg, BB(cb ^ 1) + r0 * 64);
      }
    }
    const __bf16* Al = AB(cb);
    const __bf16* Bl = BB(cb);
#pragma unroll
    for (int kk = 0; kk < 2; ++kk) {
      int gp = ((kk * 4 + quad) ^ (lc & 7)) * 8;
      bf16x8 a[4], bb[4];
#pragma unroll
      for (int mt = 0; mt < 4; mt++)
        a[mt] = *(const bf16x8*)(Al + (wr * 64 + mt * 16 + lc) * 64 + gp);
#pragma unroll
      for (int nt = 0; nt < 4; nt++)
        bb[nt] = *(const bf16x8*)(Bl + (wc * 64 + nt * 16 + lc) * 64 + gp);
#pragma unroll
      for (int mt = 0; mt < 4; mt++)
#pragma unroll
        for (int nt = 0; nt < 4; nt++)
          acc[mt][nt] = mfma16(a[mt], bb[nt], acc[mt][nt]);
    }
    __syncthreads();
  }

#pragma unroll
  for (int nt = 0; nt < 4; nt++) {
    int col = n0 + nt * 16 + lc;
    float bval = bo[col];
#pragma unroll
    for (int mt = 0; mt < 4; mt++)
#pragma unroll
      for (int r = 0; r < 4; r++) {
        int row = m0 + mt * 16 + quad * 4 + r;
        out[row * D_ + col] = acc[mt][nt][r] + bval;
      }
  }
}

extern "C" void kernel_launch(void* const* d_in, const int* in_sizes, int n_in,
                              void* d_out, int out_size, void* d_ws, size_t ws_size,
                              hipStream_t stream) {
  const float* q  = (const float*)d_in[0];
  const float* k  = (const float*)d_in[1];
  const float* v  = (const float*)d_in[2];
  const float* Wq = (const float*)d_in[3];
  const float* bq = (const float*)d_in[4];
  const float* Wk = (const float*)d_in[5];
  const float* bk = (const float*)d_in[6];
  const float* Wv = (const float*)d_in[7];
  const float* bv = (const float*)d_in[8];
  const float* Wo = (const float*)d_in[9];
  const float* bo = (const float*)d_in[10];

  char* ws = (char*)d_ws;
  __bf16* Xq  = (__bf16*)(ws + 0);          // 8 MiB each
  __bf16* Xk  = (__bf16*)(ws + 8388608);
  __bf16* Xv  = (__bf16*)(ws + 16777216);
  __bf16* Wtq = (__bf16*)(ws + 25165824);   // 512 KiB each
  __bf16* Wtk = (__bf16*)(ws + 25690112);
  __bf16* Wtv = (__bf16*)(ws + 26214400);
  __bf16* Wot = (__bf16*)(ws + 26738688);
  __bf16* Qb  = (__bf16*)(ws + 27262976);   // 8 MiB each
  __bf16* Kb  = (__bf16*)(ws + 35651584);
  __bf16* Vtb = (__bf16*)(ws + 44040192);
  __bf16* Ob  = (__bf16*)(ws + 52428800);
  int* tickets = (int*)(ws + 60817408);     // 8 per-XCD work-queue counters

  prep_all_kernel<<<12544, 256, 0, stream>>>(q, k, v, Wq, Wk, Wv, Wo,
                                             Xq, Xk, Xv, Wtq, Wtk, Wtv, Wot, tickets);
  proj_gemm_kernel<<<dim3(64, 4, 3), 256, 0, stream>>>(Xq, Xk, Xv, Wtq, Wtk, Wtv,
                                                       bq, bk, bv, Qb, Kb, Vtb);
  flash_kernel<<<dim3(512), 256, 0, stream>>>(Qb, Kb, Vtb, Ob, tickets);
  out_gemm_kernel<<<dim3(64, 4), 256, 0, stream>>>(Ob, Wot, bo, (float*)d_out);
}

// Round 7
// 179.516 us; speedup vs baseline: 1.1322x; 1.1322x over previous
//
#include <hip/hip_runtime.h>
#include <hip/hip_bf16.h>

#define B_ 4
#define S_ 2048
#define D_ 512
#define H_ 8
#define A_ 64

typedef __attribute__((ext_vector_type(8))) __bf16 bf16x8;
typedef __attribute__((ext_vector_type(4))) __bf16 bf16x4;
typedef __attribute__((ext_vector_type(4))) float f32x4;

static __device__ __forceinline__ f32x4 mfma16(bf16x8 a, bf16x8 b, f32x4 c) {
  return __builtin_amdgcn_mfma_f32_16x16x32_bf16(a, b, c, 0, 0, 0);
}

static __device__ __forceinline__ f32x4 zero4() {
  f32x4 z = {0.f, 0.f, 0.f, 0.f};
  return z;
}

// 0.125 (1/sqrt(A)) * log2(e): scores are consumed by v_exp (2^x) in flash_kernel
#define QSCALE 0.18033688011f

#if __has_builtin(__builtin_amdgcn_exp2f)
#define EXP2(x) __builtin_amdgcn_exp2f(x)
#else
#define EXP2(x) exp2f(x)
#endif

// async global->LDS, 16B per lane, lds dest = wave-uniform base + lane*16
#define GLDS(g, l)                                                      \
  __builtin_amdgcn_global_load_lds(                                     \
      (const __attribute__((address_space(1))) void*)(g),               \
      (__attribute__((address_space(3))) void*)(l), 16, 0, 0)

// ------------- merged input prep: fp32->bf16 activations + LDS-transposed weights -------------
__global__ void prep_all_kernel(const float* __restrict__ q, const float* __restrict__ k,
                                const float* __restrict__ v,
                                const float* __restrict__ Wq, const float* __restrict__ Wk,
                                const float* __restrict__ Wv, const float* __restrict__ Wo,
                                __bf16* __restrict__ xq, __bf16* __restrict__ xk,
                                __bf16* __restrict__ xv,
                                __bf16* __restrict__ tq, __bf16* __restrict__ tk,
                                __bf16* __restrict__ tv, __bf16* __restrict__ to_) {
  __shared__ float tile[64][65];
  if (blockIdx.x < 12288) {
    int idx = blockIdx.x * 256 + threadIdx.x;  // 3 * 2^20 threads, one float4 each
    int which = idx >> 20;
    int i = idx & ((1 << 20) - 1);
    const float4* s = (const float4*)(which == 0 ? q : (which == 1 ? k : v));
    __bf16* d = (which == 0) ? xq : (which == 1 ? xk : xv);
    float4 f = s[i];
    bf16x4 o;
    o.x = (__bf16)f.x; o.y = (__bf16)f.y; o.z = (__bf16)f.z; o.w = (__bf16)f.w;
    *(bf16x4*)(d + 4 * i) = o;
  } else {
    int t = blockIdx.x - 12288;   // 0..255
    if (t < 192) {
      // Wq/Wk/Wv: tq[n=h*64+a][k=d] = W[h][d][a] (coalesced both sides via LDS transpose)
      int mat = t >> 6;
      int h = (t >> 3) & 7;
      int d0 = (t & 7) * 64;
      const float* W = (mat == 0) ? Wq : (mat == 1 ? Wk : Wv);
      __bf16* dst = (mat == 0) ? tq : (mat == 1 ? tk : tv);
      float sc = (mat == 0) ? QSCALE : 1.0f;   // fold 1/sqrt(A)*log2e into Q projection
      int a = threadIdx.x & 63, r0 = threadIdx.x >> 6;
#pragma unroll
      for (int i = 0; i < 16; i++) {
        int dd = r0 * 16 + i;
        tile[dd][a] = W[(h * D_ + d0 + dd) * A_ + a] * sc;
      }
      __syncthreads();
      int dd = threadIdx.x & 63, a0 = threadIdx.x >> 6;
#pragma unroll
      for (int i = 0; i < 16; i++) {
        int a2 = a0 * 16 + i;
        dst[(h * 64 + a2) * D_ + d0 + dd] = (__bf16)tile[dd][a2];
      }
    } else {
      // Wo: Wot[n=d][k=f] = Wo[f][d]
      int t2 = t - 192;           // 0..63
      int f0 = (t2 >> 3) * 64, d0 = (t2 & 7) * 64;
      int d = threadIdx.x & 63, r0 = threadIdx.x >> 6;
#pragma unroll
      for (int i = 0; i < 16; i++) {
        int ff = r0 * 16 + i;
        tile[ff][d] = Wo[(f0 + ff) * D_ + d0 + d];
      }
      __syncthreads();
      int f = threadIdx.x & 63, a0 = threadIdx.x >> 6;
#pragma unroll
      for (int i = 0; i < 16; i++) {
        int dd = a0 * 16 + i;
        to_[(d0 + dd) * D_ + f0 + f] = (__bf16)tile[f][dd];
      }
    }
  }
}

// ---------------- QKV projection GEMM: [8192x512] @ [512x512] per matrix ----------------
// 128x128 tile, 4 waves 2x2, BK=64, double-buffered global_load_lds staging (16B-granule XOR
// swizzle on both sides). Round-4 verified.
__global__ __launch_bounds__(256) void proj_gemm_kernel(
    const __bf16* __restrict__ Xq, const __bf16* __restrict__ Xk, const __bf16* __restrict__ Xv,
    const __bf16* __restrict__ Wtq, const __bf16* __restrict__ Wtk, const __bf16* __restrict__ Wtv,
    const float* __restrict__ bq, const float* __restrict__ bk, const float* __restrict__ bv,
    __bf16* __restrict__ Qb, __bf16* __restrict__ Kb, __bf16* __restrict__ Vtb) {
  int z = blockIdx.z;
  const __bf16* X  = (z == 0) ? Xq  : (z == 1 ? Xk  : Xv);
  const __bf16* Wt = (z == 0) ? Wtq : (z == 1 ? Wtk : Wtv);
  const float* bias = (z == 0) ? bq : (z == 1 ? bk : bv);
  float bscale = (z == 0) ? QSCALE : 1.0f;

  int lane = threadIdx.x & 63, wv = threadIdx.x >> 6;
  int wr = wv >> 1, wc = wv & 1;
  int quad = lane >> 4, lc = lane & 15;
  int M0 = blockIdx.x * 128, N0 = blockIdx.y * 128;
  int m0 = M0 + wr * 64, n0 = N0 + wc * 64;

  // 64 KiB: [buf][A|B][128][64]; epilogue staging aliases this after the loop
  __shared__ __align__(16) __bf16 smem[2 * 2 * 128 * 64];
#define AB(buf) (smem + (buf) * 16384)
#define BB(buf) (smem + (buf) * 16384 + 8192)

  int srow = lane >> 3;                 // 0..7
  int sg = ((lane & 7) ^ srow) * 8;     // pre-swizzled source granule

  // prologue: stage K-step 0 into buf 0
#pragma unroll
  for (int i = 0; i < 4; ++i) {
    int r0 = wv * 32 + i * 8;
    GLDS(X  + (M0 + r0 + srow) * D_ + sg, AB(0) + r0 * 64);
    GLDS(Wt + (N0 + r0 + srow) * D_ + sg, BB(0) + r0 * 64);
  }

  f32x4 acc[4][4];
#pragma unroll
  for (int mt = 0; mt < 4; mt++)
#pragma unroll
    for (int nt = 0; nt < 4; nt++) acc[mt][nt] = zero4();

  __syncthreads();   // drains vmcnt(0): step-0 tiles staged & visible

  for (int j = 0; j < 8; ++j) {
    int cb = j & 1;
    if (j < 7) {
      int k0 = (j + 1) * 64;
#pragma unroll
      for (int i = 0; i < 4; ++i) {
        int r0 = wv * 32 + i * 8;
        GLDS(X  + (M0 + r0 + srow) * D_ + k0 + sg, AB(cb ^ 1) + r0 * 64);
        GLDS(Wt + (N0 + r0 + srow) * D_ + k0 + sg, BB(cb ^ 1) + r0 * 64);
      }
    }
    const __bf16* Al = AB(cb);
    const __bf16* Bl = BB(cb);
#pragma unroll
    for (int kk = 0; kk < 2; ++kk) {
      int gp = ((kk * 4 + quad) ^ (lc & 7)) * 8;
      bf16x8 a[4], bb[4];
#pragma unroll
      for (int mt = 0; mt < 4; mt++)
        a[mt] = *(const bf16x8*)(Al + (wr * 64 + mt * 16 + lc) * 64 + gp);
#pragma unroll
      for (int nt = 0; nt < 4; nt++)
        bb[nt] = *(const bf16x8*)(Bl + (wc * 64 + nt * 16 + lc) * 64 + gp);
#pragma unroll
      for (int mt = 0; mt < 4; mt++)
#pragma unroll
        for (int nt = 0; nt < 4; nt++)
          acc[mt][nt] = mfma16(a[mt], bb[nt], acc[mt][nt]);
    }
    __syncthreads();   // all waves done reading buf cb; next tile staged & visible
  }

  // epilogue staging aliases smem (all waves are past the loop's final barrier)
  __bf16* vlds = smem + wv * (64 * 72);

  int h = n0 >> 6;                 // one head per wave tile
  int b = m0 >> 11, s0 = m0 & (S_ - 1);
  if (z < 2) {
    // stage row-major [s-row][a-col], then 128B-contiguous row stores
#pragma unroll
    for (int nt = 0; nt < 4; nt++) {
      int col = n0 + nt * 16 + lc;
      float bval = bias[col] * bscale;
#pragma unroll
      for (int mt = 0; mt < 4; mt++)
#pragma unroll
        for (int r = 0; r < 4; r++)
          vlds[(mt * 16 + quad * 4 + r) * 72 + nt * 16 + lc] = (__bf16)(acc[mt][nt][r] + bval);
    }
    __asm__ volatile("s_waitcnt lgkmcnt(0)" ::: "memory");
    __bf16* dst = (z == 0) ? Qb : Kb;
#pragma unroll
    for (int it = 0; it < 8; it++) {
      int row = it * 8 + (lane >> 3);
      int c8 = (lane & 7) * 8;
      bf16x8 vv = *(const bf16x8*)(vlds + row * 72 + c8);
      *(bf16x8*)(dst + ((b * H_ + h) * S_ + s0 + row) * A_ + c8) = vv;   // [B,H,S,A]
    }
  } else {
    // V: stage transposed [a-row][s-col] (packed b64 writes), coalesced [B,H,A,S] stores
#pragma unroll
    for (int nt = 0; nt < 4; nt++) {
      int col = n0 + nt * 16 + lc;
      float bval = bias[col];
#pragma unroll
      for (int mt = 0; mt < 4; mt++) {
        bf16x4 pk;
#pragma unroll
        for (int r = 0; r < 4; r++) pk[r] = (__bf16)(acc[mt][nt][r] + bval);
        *(bf16x4*)(vlds + (nt * 16 + lc) * 72 + mt * 16 + quad * 4) = pk;
      }
    }
    __asm__ volatile("s_waitcnt lgkmcnt(0)" ::: "memory");
#pragma unroll
    for (int it = 0; it < 8; it++) {
      int a_l = it * 8 + (lane >> 3);
      int s_l = (lane & 7) * 8;
      bf16x8 vvv = *(const bf16x8*)(vlds + a_l * 72 + s_l);
      *(bf16x8*)(Vtb + ((b * H_ + h) * A_ + a_l) * S_ + s0 + s_l) = vvv;
    }
  }
}

// ---------------- flash attention: self-balanced paired-strip blocks ----------------
// 256 blocks (1/CU), 8 waves (512 threads). Block = (bh, pair p): q-groups b1=p (long) and
// b2=15-p (short) IN THE SAME BLOCK. The short group's key-tile range [30-2p,32) is a subset
// of the long group's [2p,32), so one shared K/V LDS stream (double-buffered global_load_lds,
// 16B-granule XOR swizzle) serves both. Per-block compute = (32-2p)+(2+2p) = 34 half-tile
// units for EVERY block -> balance holds for ANY dispatch->CU map (R5 static pairing and R6
// ticket queue both guessed wrong maps). Wave w owns rows [b*128+w*16,+16) of each group;
// P-LDS (16 rows/wave) is time-shared group1-then-group2, keeping LDS at 51.2 KB.
// XCD pinning blockIdx&7 -> bh group kept (12 MB FETCH verified). p==7 blocks (fewest
// iterations) do the fused row-2047 fix (O = mean(V)).
__global__ __launch_bounds__(512) void flash_kernel(const __bf16* __restrict__ Q,
                                                    const __bf16* __restrict__ K,
                                                    const __bf16* __restrict__ Vt,
                                                    __bf16* __restrict__ O) {
  int id = blockIdx.x;                    // 0..255
  int xcd = id & 7, slot = id >> 3;       // slot 0..31
  int p = slot >> 2;                      // pair 0..7
  int bh = xcd * 4 + (slot & 3);          // 4 bh per XCD: K+V L2-resident
  int lane = threadIdx.x & 63, wv = threadIdx.x >> 6;   // wv 0..7
  int quad = lane >> 4, lc = lane & 15;
  int R1 = p * 128 + wv * 16;             // group1 (long) first row for this wave
  int R2 = (15 - p) * 128 + wv * 16;      // group2 (short) first row
  int t0 = 2 * p, ntile = 32 - 2 * p;

  const __bf16* Qp = Q + bh * S_ * A_;   // [S][64]
  const __bf16* Kp = K + bh * S_ * A_;   // [S][64]
  const __bf16* Vp = Vt + bh * A_ * S_;  // [64][S]

  __shared__ __align__(16) __bf16 kvbuf[2][2][64][64];   // [buf][0=K,1=V][row][64] = 32 KiB
  __shared__ __align__(16) __bf16 plds_all[8][16][72];   // per-wave P staging (time-shared)
  __bf16* plds = &plds_all[wv][0][0];

  int srow = lane >> 3;                  // 0..7
  int sg = ((lane & 7) ^ srow) * 8;      // swizzled source granule
  int wr8 = wv * 8;                      // staging rows: 8 waves x 8 rows = 64

  // ---- prologue: stage tile t0 into buf0 ----
  {
    int kt = t0 << 6;
    GLDS(Kp + (kt + wr8 + srow) * A_ + sg, &kvbuf[0][0][wr8][0]);
    GLDS(Vp + (wr8 + srow) * S_ + kt + sg, &kvbuf[0][1][wr8][0]);
  }

  bf16x8 qf1[2], qf2[2];
  qf1[0] = *(const bf16x8*)(Qp + (R1 + lc) * A_ + quad * 8);
  qf1[1] = *(const bf16x8*)(Qp + (R1 + lc) * A_ + 32 + quad * 8);
  qf2[0] = *(const bf16x8*)(Qp + (R2 + lc) * A_ + quad * 8);
  qf2[1] = *(const bf16x8*)(Qp + (R2 + lc) * A_ + 32 + quad * 8);

  f32x4 o1[4], o2[4];
  float ls1[4], ls2[4];
#pragma unroll
  for (int t = 0; t < 4; t++) { o1[t] = zero4(); o2[t] = zero4(); ls1[t] = 0.f; ls2[t] = 0.f; }

  int g0 = (quad ^ (lc & 7)) * 8;        // swizzled granule offsets for frag reads
  int g1 = ((quad + 4) ^ (lc & 7)) * 8;

  __syncthreads();   // drains vmcnt(0): tile t0 staged & visible

  for (int j = 0; j < ntile; ++j) {
    int t = t0 + j;
    int cb = j & 1;
    if (j + 1 < ntile) {
      int ktn = (t + 1) << 6;
      GLDS(Kp + (ktn + wr8 + srow) * A_ + sg, &kvbuf[cb ^ 1][0][wr8][0]);
      GLDS(Vp + (wr8 + srow) * S_ + ktn + sg, &kvbuf[cb ^ 1][1][wr8][0]);
    }
    const __bf16* Kl = &kvbuf[cb][0][0][0];
    const __bf16* Vl = &kvbuf[cb][1][0][0];

    // ---------------- group 1 (always active) ----------------
    {
      f32x4 sc[4];
#pragma unroll
      for (int nt = 0; nt < 4; nt++) {
        int rr = nt * 16 + lc;
        bf16x8 kf0 = *(const bf16x8*)(Kl + rr * 64 + g0);
        bf16x8 kf1 = *(const bf16x8*)(Kl + rr * 64 + g1);
        f32x4 ss = zero4();
        ss = mfma16(qf1[0], kf0, ss);
        ss = mfma16(qf1[1], kf1, ss);
        sc[nt] = ss;
      }
      if (t * 64 <= R1 + 15) {           // diagonal (or fully-masked) tile
#pragma unroll
        for (int nt = 0; nt < 4; nt++) {
          int col = t * 64 + nt * 16 + lc;
#pragma unroll
          for (int r = 0; r < 4; r++) {
            int row = R1 + quad * 4 + r;
            float pv = (col <= row) ? 0.0f : EXP2(sc[nt][r]);
            ls1[r] += pv;
            plds[(quad * 4 + r) * 72 + nt * 16 + lc] = (__bf16)pv;
          }
        }
      } else {
#pragma unroll
        for (int nt = 0; nt < 4; nt++)
#pragma unroll
          for (int r = 0; r < 4; r++) {
            float pv = EXP2(sc[nt][r]);
            ls1[r] += pv;
            plds[(quad * 4 + r) * 72 + nt * 16 + lc] = (__bf16)pv;
          }
      }
      __asm__ volatile("s_waitcnt lgkmcnt(0)" ::: "memory");
      bf16x8 pf0 = *(const bf16x8*)(plds + lc * 72 + quad * 8);
      bf16x8 pf1 = *(const bf16x8*)(plds + lc * 72 + 32 + quad * 8);
      __builtin_amdgcn_s_setprio(1);
#pragma unroll
      for (int ot = 0; ot < 4; ot++) {
        int rr = ot * 16 + lc;
        bf16x8 vf0 = *(const bf16x8*)(Vl + rr * 64 + g0);
        bf16x8 vf1 = *(const bf16x8*)(Vl + rr * 64 + g1);
        o1[ot] = mfma16(pf0, vf0, o1[ot]);
        o1[ot] = mfma16(pf1, vf1, o1[ot]);
      }
      __builtin_amdgcn_s_setprio(0);
    }

    // ---------------- group 2 (active near the end of the tile range) ----------------
    if (t * 64 + 63 > R2) {
      f32x4 sc[4];
#pragma unroll
      for (int nt = 0; nt < 4; nt++) {
        int rr = nt * 16 + lc;
        bf16x8 kf0 = *(const bf16x8*)(Kl + rr * 64 + g0);
        bf16x8 kf1 = *(const bf16x8*)(Kl + rr * 64 + g1);
        f32x4 ss = zero4();
        ss = mfma16(qf2[0], kf0, ss);
        ss = mfma16(qf2[1], kf1, ss);
        sc[nt] = ss;
      }
      if (t * 64 <= R2 + 15) {
#pragma unroll
        for (int nt = 0; nt < 4; nt++) {
          int col = t * 64 + nt * 16 + lc;
#pragma unroll
          for (int r = 0; r < 4; r++) {
            int row = R2 + quad * 4 + r;
            float pv = (col <= row) ? 0.0f : EXP2(sc[nt][r]);
            ls2[r] += pv;
            plds[(quad * 4 + r) * 72 + nt * 16 + lc] = (__bf16)pv;
          }
        }
      } else {
#pragma unroll
        for (int nt = 0; nt < 4; nt++)
#pragma unroll
          for (int r = 0; r < 4; r++) {
            float pv = EXP2(sc[nt][r]);
            ls2[r] += pv;
            plds[(quad * 4 + r) * 72 + nt * 16 + lc] = (__bf16)pv;
          }
      }
      __asm__ volatile("s_waitcnt lgkmcnt(0)" ::: "memory");
      bf16x8 pf0 = *(const bf16x8*)(plds + lc * 72 + quad * 8);
      bf16x8 pf1 = *(const bf16x8*)(plds + lc * 72 + 32 + quad * 8);
      __builtin_amdgcn_s_setprio(1);
#pragma unroll
      for (int ot = 0; ot < 4; ot++) {
        int rr = ot * 16 + lc;
        bf16x8 vf0 = *(const bf16x8*)(Vl + rr * 64 + g0);
        bf16x8 vf1 = *(const bf16x8*)(Vl + rr * 64 + g1);
        o2[ot] = mfma16(pf0, vf0, o2[ot]);
        o2[ot] = mfma16(pf1, vf1, o2[ot]);
      }
      __builtin_amdgcn_s_setprio(0);
    }
    __syncthreads();   // all waves done reading buf cb; next tile staged & visible
  }

  // ---- reduce row-sums across the 16 lc lanes (offsets 1..8 stay in-group) ----
#pragma unroll
  for (int r = 0; r < 4; r++) {
    float l1 = ls1[r], l2 = ls2[r];
#pragma unroll
    for (int off = 1; off < 16; off <<= 1) { l1 += __shfl_xor(l1, off, 64); l2 += __shfl_xor(l2, off, 64); }
    ls1[r] = l1; ls2[r] = l2;
  }

  int b = bh >> 3, h = bh & 7;

  // ---- epilogue group 1: normalize into per-wave LDS tile, 16B coalesced stores ----
#pragma unroll
  for (int r = 0; r < 4; r++) {
    float rl = 1.0f / ls1[r];
#pragma unroll
    for (int ot = 0; ot < 4; ot++)
      plds[(quad * 4 + r) * 72 + ot * 16 + lc] = (__bf16)(o1[ot][r] * rl);
  }
  __asm__ volatile("s_waitcnt lgkmcnt(0)" ::: "memory");
#pragma unroll
  for (int it = 0; it < 2; it++) {
    int row = it * 8 + (lane >> 3);
    int c8 = (lane & 7) * 8;
    *(bf16x8*)(O + (b * S_ + R1 - wv * 16 + wv * 16 + row) * (H_ * A_) + h * 64 + c8) =
        *(const bf16x8*)(plds + row * 72 + c8);
  }

  // ---- epilogue group 2 (skip row 2047: NaN from 1/0; p==7 block rewrites it) ----
#pragma unroll
  for (int r = 0; r < 4; r++) {
    float rl = 1.0f / ls2[r];
#pragma unroll
    for (int ot = 0; ot < 4; ot++)
      plds[(quad * 4 + r) * 72 + ot * 16 + lc] = (__bf16)(o2[ot][r] * rl);
  }
  __asm__ volatile("s_waitcnt lgkmcnt(0)" ::: "memory");
#pragma unroll
  for (int it = 0; it < 2; it++) {
    int row = it * 8 + (lane >> 3);
    int c8 = (lane & 7) * 8;
    int grow = R2 + row;
    if (grow != S_ - 1)
      *(bf16x8*)(O + (b * S_ + grow) * (H_ * A_) + h * 64 + c8) =
          *(const bf16x8*)(plds + row * 72 + c8);
  }

  // ---- fused row-2047 fix: softmax over all -1e9 is uniform -> O = mean(V) ----
  if (p == 7) {
    int a = threadIdx.x >> 3;       // 0..63
    int li = threadIdx.x & 7;       // 8 lanes per a-row
    const __bf16* src = Vp + a * S_;
    float ssum = 0.f;
#pragma unroll 8
    for (int j2 = 0; j2 < 32; j2++) {
      bf16x8 vv = *(const bf16x8*)(src + (j2 * 8 + li) * 8);
#pragma unroll
      for (int e = 0; e < 8; e++) ssum += (float)vv[e];
    }
    ssum += __shfl_xor(ssum, 1, 64);
    ssum += __shfl_xor(ssum, 2, 64);
    ssum += __shfl_xor(ssum, 4, 64);
    if (li == 0)
      O[(b * S_ + (S_ - 1)) * (H_ * A_) + h * 64 + a] = (__bf16)(ssum * (1.0f / 2048.0f));
  }
}

// ---------------- output projection: [8192x512] @ [512x512] + bo, fp32 out ----------------
// Same LDS-staged BK=64 double-buffered main loop as proj_gemm; direct fp32 epilogue stores.
__global__ __launch_bounds__(256) void out_gemm_kernel(const __bf16* __restrict__ Ob,
                                                       const __bf16* __restrict__ Wot,
                                                       const float* __restrict__ bo,
                                                       float* __restrict__ out) {
  int lane = threadIdx.x & 63, wv = threadIdx.x >> 6;
  int wr = wv >> 1, wc = wv & 1;
  int quad = lane >> 4, lc = lane & 15;
  int M0 = blockIdx.x * 128, N0 = blockIdx.y * 128;
  int m0 = M0 + wr * 64, n0 = N0 + wc * 64;

  __shared__ __align__(16) __bf16 smem[2 * 2 * 128 * 64];

  int srow = lane >> 3;
  int sg = ((lane & 7) ^ srow) * 8;

#pragma unroll
  for (int i = 0; i < 4; ++i) {
    int r0 = wv * 32 + i * 8;
    GLDS(Ob  + (M0 + r0 + srow) * D_ + sg, AB(0) + r0 * 64);
    GLDS(Wot + (N0 + r0 + srow) * D_ + sg, BB(0) + r0 * 64);
  }

  f32x4 acc[4][4];
#pragma unroll
  for (int mt = 0; mt < 4; mt++)
#pragma unroll
    for (int nt = 0; nt < 4; nt++) acc[mt][nt] = zero4();

  __syncthreads();

  for (int j = 0; j < 8; ++j) {
    int cb = j & 1;
    if (j < 7) {
      int k0 = (j + 1) * 64;
#pragma unroll
      for (int i = 0; i < 4; ++i) {
        int r0 = wv * 32 + i * 8;
        GLDS(Ob  + (M0 + r0 + srow) * D_ + k0 + sg, AB(cb ^ 1) + r0 * 64);
        GLDS(Wot + (N0 + r0 + srow) * D_ + k0 + sg, BB(cb ^ 1) + r0 * 64);
      }
    }
    const __bf16* Al = AB(cb);
    const __bf16* Bl = BB(cb);
#pragma unroll
    for (int kk = 0; kk < 2; ++kk) {
      int gp = ((kk * 4 + quad) ^ (lc & 7)) * 8;
      bf16x8 a[4], bb[4];
#pragma unroll
      for (int mt = 0; mt < 4; mt++)
        a[mt] = *(const bf16x8*)(Al + (wr * 64 + mt * 16 + lc) * 64 + gp);
#pragma unroll
      for (int nt = 0; nt < 4; nt++)
        bb[nt] = *(const bf16x8*)(Bl + (wc * 64 + nt * 16 + lc) * 64 + gp);
#pragma unroll
      for (int mt = 0; mt < 4; mt++)
#pragma unroll
        for (int nt = 0; nt < 4; nt++)
          acc[mt][nt] = mfma16(a[mt], bb[nt], acc[mt][nt]);
    }
    __syncthreads();
  }

#pragma unroll
  for (int nt = 0; nt < 4; nt++) {
    int col = n0 + nt * 16 + lc;
    float bval = bo[col];
#pragma unroll
    for (int mt = 0; mt < 4; mt++)
#pragma unroll
      for (int r = 0; r < 4; r++) {
        int row = m0 + mt * 16 + quad * 4 + r;
        out[row * D_ + col] = acc[mt][nt][r] + bval;
      }
  }
}

extern "C" void kernel_launch(void* const* d_in, const int* in_sizes, int n_in,
                              void* d_out, int out_size, void* d_ws, size_t ws_size,
                              hipStream_t stream) {
  const float* q  = (const float*)d_in[0];
  const float* k  = (const float*)d_in[1];
  const float* v  = (const float*)d_in[2];
  const float* Wq = (const float*)d_in[3];
  const float* bq = (const float*)d_in[4];
  const float* Wk = (const float*)d_in[5];
  const float* bk = (const float*)d_in[6];
  const float* Wv = (const float*)d_in[7];
  const float* bv = (const float*)d_in[8];
  const float* Wo = (const float*)d_in[9];
  const float* bo = (const float*)d_in[10];

  char* ws = (char*)d_ws;
  __bf16* Xq  = (__bf16*)(ws + 0);          // 8 MiB each
  __bf16* Xk  = (__bf16*)(ws + 8388608);
  __bf16* Xv  = (__bf16*)(ws + 16777216);
  __bf16* Wtq = (__bf16*)(ws + 25165824);   // 512 KiB each
  __bf16* Wtk = (__bf16*)(ws + 25690112);
  __bf16* Wtv = (__bf16*)(ws + 26214400);
  __bf16* Wot = (__bf16*)(ws + 26738688);
  __bf16* Qb  = (__bf16*)(ws + 27262976);   // 8 MiB each
  __bf16* Kb  = (__bf16*)(ws + 35651584);
  __bf16* Vtb = (__bf16*)(ws + 44040192);
  __bf16* Ob  = (__bf16*)(ws + 52428800);

  prep_all_kernel<<<12544, 256, 0, stream>>>(q, k, v, Wq, Wk, Wv, Wo,
                                             Xq, Xk, Xv, Wtq, Wtk, Wtv, Wot);
  proj_gemm_kernel<<<dim3(64, 4, 3), 256, 0, stream>>>(Xq, Xk, Xv, Wtq, Wtk, Wtv,
                                                       bq, bk, bv, Qb, Kb, Vtb);
  flash_kernel<<<dim3(256), 512, 0, stream>>>(Qb, Kb, Vtb, Ob);
  out_gemm_kernel<<<dim3(64, 4), 256, 0, stream>>>(Ob, Wot, bo, (float*)d_out);
}

// Round 8
// 174.568 us; speedup vs baseline: 1.1643x; 1.0283x over previous
//
#include <hip/hip_runtime.h>
#include <hip/hip_bf16.h>

#define B_ 4
#define S_ 2048
#define D_ 512
#define H_ 8
#define A_ 64

typedef __attribute__((ext_vector_type(8))) __bf16 bf16x8;
typedef __attribute__((ext_vector_type(4))) __bf16 bf16x4;
typedef __attribute__((ext_vector_type(4))) float f32x4;

static __device__ __forceinline__ f32x4 mfma16(bf16x8 a, bf16x8 b, f32x4 c) {
  return __builtin_amdgcn_mfma_f32_16x16x32_bf16(a, b, c, 0, 0, 0);
}

static __device__ __forceinline__ f32x4 zero4() {
  f32x4 z = {0.f, 0.f, 0.f, 0.f};
  return z;
}

// 0.125 (1/sqrt(A)) * log2(e): scores are consumed by v_exp (2^x) in flash_kernel
#define QSCALE 0.18033688011f

#if __has_builtin(__builtin_amdgcn_exp2f)
#define EXP2(x) __builtin_amdgcn_exp2f(x)
#else
#define EXP2(x) exp2f(x)
#endif

// async global->LDS, 16B per lane, lds dest = wave-uniform base + lane*16
#define GLDS(g, l)                                                      \
  __builtin_amdgcn_global_load_lds(                                     \
      (const __attribute__((address_space(1))) void*)(g),               \
      (__attribute__((address_space(3))) void*)(l), 16, 0, 0)

// ------------- merged input prep: fp32->bf16 activations + LDS-transposed weights -------------
__global__ void prep_all_kernel(const float* __restrict__ q, const float* __restrict__ k,
                                const float* __restrict__ v,
                                const float* __restrict__ Wq, const float* __restrict__ Wk,
                                const float* __restrict__ Wv, const float* __restrict__ Wo,
                                __bf16* __restrict__ xq, __bf16* __restrict__ xk,
                                __bf16* __restrict__ xv,
                                __bf16* __restrict__ tq, __bf16* __restrict__ tk,
                                __bf16* __restrict__ tv, __bf16* __restrict__ to_) {
  __shared__ float tile[64][65];
  if (blockIdx.x < 12288) {
    int idx = blockIdx.x * 256 + threadIdx.x;  // 3 * 2^20 threads, one float4 each
    int which = idx >> 20;
    int i = idx & ((1 << 20) - 1);
    const float4* s = (const float4*)(which == 0 ? q : (which == 1 ? k : v));
    __bf16* d = (which == 0) ? xq : (which == 1 ? xk : xv);
    float4 f = s[i];
    bf16x4 o;
    o.x = (__bf16)f.x; o.y = (__bf16)f.y; o.z = (__bf16)f.z; o.w = (__bf16)f.w;
    *(bf16x4*)(d + 4 * i) = o;
  } else {
    int t = blockIdx.x - 12288;   // 0..255
    if (t < 192) {
      // Wq/Wk/Wv: tq[n=h*64+a][k=d] = W[h][d][a] (coalesced both sides via LDS transpose)
      int mat = t >> 6;
      int h = (t >> 3) & 7;
      int d0 = (t & 7) * 64;
      const float* W = (mat == 0) ? Wq : (mat == 1 ? Wk : Wv);
      __bf16* dst = (mat == 0) ? tq : (mat == 1 ? tk : tv);
      float sc = (mat == 0) ? QSCALE : 1.0f;   // fold 1/sqrt(A)*log2e into Q projection
      int a = threadIdx.x & 63, r0 = threadIdx.x >> 6;
#pragma unroll
      for (int i = 0; i < 16; i++) {
        int dd = r0 * 16 + i;
        tile[dd][a] = W[(h * D_ + d0 + dd) * A_ + a] * sc;
      }
      __syncthreads();
      int dd = threadIdx.x & 63, a0 = threadIdx.x >> 6;
#pragma unroll
      for (int i = 0; i < 16; i++) {
        int a2 = a0 * 16 + i;
        dst[(h * 64 + a2) * D_ + d0 + dd] = (__bf16)tile[dd][a2];
      }
    } else {
      // Wo: Wot[n=d][k=f] = Wo[f][d]
      int t2 = t - 192;           // 0..63
      int f0 = (t2 >> 3) * 64, d0 = (t2 & 7) * 64;
      int d = threadIdx.x & 63, r0 = threadIdx.x >> 6;
#pragma unroll
      for (int i = 0; i < 16; i++) {
        int ff = r0 * 16 + i;
        tile[ff][d] = Wo[(f0 + ff) * D_ + d0 + d];
      }
      __syncthreads();
      int f = threadIdx.x & 63, a0 = threadIdx.x >> 6;
#pragma unroll
      for (int i = 0; i < 16; i++) {
        int dd = a0 * 16 + i;
        to_[(d0 + dd) * D_ + f0 + f] = (__bf16)tile[f][dd];
      }
    }
  }
}

// ---------------- QKV projection GEMM: [8192x512] @ [512x512] per matrix ----------------
// 128x128 tile, 4 waves 2x2, BK=64, double-buffered global_load_lds staging (16B-granule XOR
// swizzle on both sides). Round-4 verified.
__global__ __launch_bounds__(256) void proj_gemm_kernel(
    const __bf16* __restrict__ Xq, const __bf16* __restrict__ Xk, const __bf16* __restrict__ Xv,
    const __bf16* __restrict__ Wtq, const __bf16* __restrict__ Wtk, const __bf16* __restrict__ Wtv,
    const float* __restrict__ bq, const float* __restrict__ bk, const float* __restrict__ bv,
    __bf16* __restrict__ Qb, __bf16* __restrict__ Kb, __bf16* __restrict__ Vtb) {
  int z = blockIdx.z;
  const __bf16* X  = (z == 0) ? Xq  : (z == 1 ? Xk  : Xv);
  const __bf16* Wt = (z == 0) ? Wtq : (z == 1 ? Wtk : Wtv);
  const float* bias = (z == 0) ? bq : (z == 1 ? bk : bv);
  float bscale = (z == 0) ? QSCALE : 1.0f;

  int lane = threadIdx.x & 63, wv = threadIdx.x >> 6;
  int wr = wv >> 1, wc = wv & 1;
  int quad = lane >> 4, lc = lane & 15;
  int M0 = blockIdx.x * 128, N0 = blockIdx.y * 128;
  int m0 = M0 + wr * 64, n0 = N0 + wc * 64;

  // 64 KiB: [buf][A|B][128][64]; epilogue staging aliases this after the loop
  __shared__ __align__(16) __bf16 smem[2 * 2 * 128 * 64];
#define AB(buf) (smem + (buf) * 16384)
#define BB(buf) (smem + (buf) * 16384 + 8192)

  int srow = lane >> 3;                 // 0..7
  int sg = ((lane & 7) ^ srow) * 8;     // pre-swizzled source granule

  // prologue: stage K-step 0 into buf 0
#pragma unroll
  for (int i = 0; i < 4; ++i) {
    int r0 = wv * 32 + i * 8;
    GLDS(X  + (M0 + r0 + srow) * D_ + sg, AB(0) + r0 * 64);
    GLDS(Wt + (N0 + r0 + srow) * D_ + sg, BB(0) + r0 * 64);
  }

  f32x4 acc[4][4];
#pragma unroll
  for (int mt = 0; mt < 4; mt++)
#pragma unroll
    for (int nt = 0; nt < 4; nt++) acc[mt][nt] = zero4();

  __syncthreads();   // drains vmcnt(0): step-0 tiles staged & visible

  for (int j = 0; j < 8; ++j) {
    int cb = j & 1;
    if (j < 7) {
      int k0 = (j + 1) * 64;
#pragma unroll
      for (int i = 0; i < 4; ++i) {
        int r0 = wv * 32 + i * 8;
        GLDS(X  + (M0 + r0 + srow) * D_ + k0 + sg, AB(cb ^ 1) + r0 * 64);
        GLDS(Wt + (N0 + r0 + srow) * D_ + k0 + sg, BB(cb ^ 1) + r0 * 64);
      }
    }
    const __bf16* Al = AB(cb);
    const __bf16* Bl = BB(cb);
#pragma unroll
    for (int kk = 0; kk < 2; ++kk) {
      int gp = ((kk * 4 + quad) ^ (lc & 7)) * 8;
      bf16x8 a[4], bb[4];
#pragma unroll
      for (int mt = 0; mt < 4; mt++)
        a[mt] = *(const bf16x8*)(Al + (wr * 64 + mt * 16 + lc) * 64 + gp);
#pragma unroll
      for (int nt = 0; nt < 4; nt++)
        bb[nt] = *(const bf16x8*)(Bl + (wc * 64 + nt * 16 + lc) * 64 + gp);
#pragma unroll
      for (int mt = 0; mt < 4; mt++)
#pragma unroll
        for (int nt = 0; nt < 4; nt++)
          acc[mt][nt] = mfma16(a[mt], bb[nt], acc[mt][nt]);
    }
    __syncthreads();   // all waves done reading buf cb; next tile staged & visible
  }

  // epilogue staging aliases smem (all waves are past the loop's final barrier)
  __bf16* vlds = smem + wv * (64 * 72);

  int h = n0 >> 6;                 // one head per wave tile
  int b = m0 >> 11, s0 = m0 & (S_ - 1);
  if (z < 2) {
    // stage row-major [s-row][a-col], then 128B-contiguous row stores
#pragma unroll
    for (int nt = 0; nt < 4; nt++) {
      int col = n0 + nt * 16 + lc;
      float bval = bias[col] * bscale;
#pragma unroll
      for (int mt = 0; mt < 4; mt++)
#pragma unroll
        for (int r = 0; r < 4; r++)
          vlds[(mt * 16 + quad * 4 + r) * 72 + nt * 16 + lc] = (__bf16)(acc[mt][nt][r] + bval);
    }
    __asm__ volatile("s_waitcnt lgkmcnt(0)" ::: "memory");
    __bf16* dst = (z == 0) ? Qb : Kb;
#pragma unroll
    for (int it = 0; it < 8; it++) {
      int row = it * 8 + (lane >> 3);
      int c8 = (lane & 7) * 8;
      bf16x8 vv = *(const bf16x8*)(vlds + row * 72 + c8);
      *(bf16x8*)(dst + ((b * H_ + h) * S_ + s0 + row) * A_ + c8) = vv;   // [B,H,S,A]
    }
  } else {
    // V: stage transposed [a-row][s-col] (packed b64 writes), coalesced [B,H,A,S] stores
#pragma unroll
    for (int nt = 0; nt < 4; nt++) {
      int col = n0 + nt * 16 + lc;
      float bval = bias[col];
#pragma unroll
      for (int mt = 0; mt < 4; mt++) {
        bf16x4 pk;
#pragma unroll
        for (int r = 0; r < 4; r++) pk[r] = (__bf16)(acc[mt][nt][r] + bval);
        *(bf16x4*)(vlds + (nt * 16 + lc) * 72 + mt * 16 + quad * 4) = pk;
      }
    }
    __asm__ volatile("s_waitcnt lgkmcnt(0)" ::: "memory");
#pragma unroll
    for (int it = 0; it < 8; it++) {
      int a_l = it * 8 + (lane >> 3);
      int s_l = (lane & 7) * 8;
      bf16x8 vvv = *(const bf16x8*)(vlds + a_l * 72 + s_l);
      *(bf16x8*)(Vtb + ((b * H_ + h) * A_ + a_l) * S_ + s0 + s_l) = vvv;
    }
  }
}

// ---------------- flash attention: self-balanced paired strips + swapped-QK lane-local P ----
// Structure as round-7 winner (256 blocks, 8 waves, long strip p + short strip 15-p per block,
// shared K/V LDS stream, 34 half-tile units per block for ANY dispatch map).
// This round: scores computed as mfma(K, Q) -> C[col=lane&15 = q-row][row = key]. Each lane
// then holds 16 P values of ONE q-row (= lc), so:
//   - P -> LDS becomes 4x ds_write_b64 (bf16x4 per nt) instead of 16x ds_write_b16
//     (removes 12 of ~34 LDS ops per unit; the scalar-write bank conflicts vanish);
//   - lsum is a single per-lane scalar; reduced with 2 shfl_xor (16,32) instead of 4;
//   - PV read side unchanged (same A-fragment addresses as before).
// K/Q fragment LDS reads are IDENTICAL to the unswapped version (both load rows at lc) --
// only the mfma argument order changes.
__global__ __launch_bounds__(512) void flash_kernel(const __bf16* __restrict__ Q,
                                                    const __bf16* __restrict__ K,
                                                    const __bf16* __restrict__ Vt,
                                                    __bf16* __restrict__ O) {
  int id = blockIdx.x;                    // 0..255
  int xcd = id & 7, slot = id >> 3;       // slot 0..31
  int p = slot >> 2;                      // pair 0..7
  int bh = xcd * 4 + (slot & 3);          // 4 bh per XCD: K+V L2-resident
  int lane = threadIdx.x & 63, wv = threadIdx.x >> 6;   // wv 0..7
  int quad = lane >> 4, lc = lane & 15;
  int R1 = p * 128 + wv * 16;             // group1 (long) first row for this wave
  int R2 = (15 - p) * 128 + wv * 16;      // group2 (short) first row
  int t0 = 2 * p, ntile = 32 - 2 * p;

  const __bf16* Qp = Q + bh * S_ * A_;   // [S][64]
  const __bf16* Kp = K + bh * S_ * A_;   // [S][64]
  const __bf16* Vp = Vt + bh * A_ * S_;  // [64][S]

  __shared__ __align__(16) __bf16 kvbuf[2][2][64][64];   // [buf][0=K,1=V][row][64] = 32 KiB
  __shared__ __align__(16) __bf16 plds_all[8][16][72];   // per-wave P staging (time-shared)
  __bf16* plds = &plds_all[wv][0][0];

  int srow = lane >> 3;                  // 0..7
  int sg = ((lane & 7) ^ srow) * 8;      // swizzled source granule
  int wr8 = wv * 8;                      // staging rows: 8 waves x 8 rows = 64

  // ---- prologue: stage tile t0 into buf0 ----
  {
    int kt = t0 << 6;
    GLDS(Kp + (kt + wr8 + srow) * A_ + sg, &kvbuf[0][0][wr8][0]);
    GLDS(Vp + (wr8 + srow) * S_ + kt + sg, &kvbuf[0][1][wr8][0]);
  }

  bf16x8 qf1[2], qf2[2];
  qf1[0] = *(const bf16x8*)(Qp + (R1 + lc) * A_ + quad * 8);
  qf1[1] = *(const bf16x8*)(Qp + (R1 + lc) * A_ + 32 + quad * 8);
  qf2[0] = *(const bf16x8*)(Qp + (R2 + lc) * A_ + quad * 8);
  qf2[1] = *(const bf16x8*)(Qp + (R2 + lc) * A_ + 32 + quad * 8);

  f32x4 o1[4], o2[4];
  float ls1 = 0.f, ls2 = 0.f;            // per-lane partial row-sum for q-row R+lc
#pragma unroll
  for (int t = 0; t < 4; t++) { o1[t] = zero4(); o2[t] = zero4(); }

  int g0 = (quad ^ (lc & 7)) * 8;        // swizzled granule offsets for frag reads
  int g1 = ((quad + 4) ^ (lc & 7)) * 8;

  __syncthreads();   // drains vmcnt(0): tile t0 staged & visible

  for (int j = 0; j < ntile; ++j) {
    int t = t0 + j;
    int cb = j & 1;
    if (j + 1 < ntile) {
      int ktn = (t + 1) << 6;
      GLDS(Kp + (ktn + wr8 + srow) * A_ + sg, &kvbuf[cb ^ 1][0][wr8][0]);
      GLDS(Vp + (wr8 + srow) * S_ + ktn + sg, &kvbuf[cb ^ 1][1][wr8][0]);
    }
    const __bf16* Kl = &kvbuf[cb][0][0][0];
    const __bf16* Vl = &kvbuf[cb][1][0][0];

    // ---------------- group 1 (always active) ----------------
    {
      f32x4 sc[4];
#pragma unroll
      for (int nt = 0; nt < 4; nt++) {
        int rr = nt * 16 + lc;
        bf16x8 kf0 = *(const bf16x8*)(Kl + rr * 64 + g0);
        bf16x8 kf1 = *(const bf16x8*)(Kl + rr * 64 + g1);
        f32x4 ss = zero4();
        ss = mfma16(kf0, qf1[0], ss);     // swapped: C[q-row=lc][key=quad*4+r+16nt]
        ss = mfma16(kf1, qf1[1], ss);
        sc[nt] = ss;
      }
      if (t * 64 <= R1 + 15) {           // diagonal region: mask col <= row -> 0
        int row = R1 + lc;
#pragma unroll
        for (int nt = 0; nt < 4; nt++)
#pragma unroll
          for (int r = 0; r < 4; r++) {
            int col = t * 64 + nt * 16 + quad * 4 + r;
            float pv = (col <= row) ? 0.0f : EXP2(sc[nt][r]);
            ls1 += pv;
            sc[nt][r] = pv;
          }
      } else {
#pragma unroll
        for (int nt = 0; nt < 4; nt++)
#pragma unroll
          for (int r = 0; r < 4; r++) {
            float pv = EXP2(sc[nt][r]);
            ls1 += pv;
            sc[nt][r] = pv;
          }
      }
      // packed P store: row lc, keys 16nt+4quad..+3 -> one b64 per nt
#pragma unroll
      for (int nt = 0; nt < 4; nt++) {
        bf16x4 pk;
#pragma unroll
        for (int r = 0; r < 4; r++) pk[r] = (__bf16)sc[nt][r];
        *(bf16x4*)(plds + lc * 72 + nt * 16 + quad * 4) = pk;
      }
      __asm__ volatile("s_waitcnt lgkmcnt(0)" ::: "memory");
      bf16x8 pf0 = *(const bf16x8*)(plds + lc * 72 + quad * 8);
      bf16x8 pf1 = *(const bf16x8*)(plds + lc * 72 + 32 + quad * 8);
      __builtin_amdgcn_s_setprio(1);
#pragma unroll
      for (int ot = 0; ot < 4; ot++) {
        int rr = ot * 16 + lc;
        bf16x8 vf0 = *(const bf16x8*)(Vl + rr * 64 + g0);
        bf16x8 vf1 = *(const bf16x8*)(Vl + rr * 64 + g1);
        o1[ot] = mfma16(pf0, vf0, o1[ot]);
        o1[ot] = mfma16(pf1, vf1, o1[ot]);
      }
      __builtin_amdgcn_s_setprio(0);
    }

    // ---------------- group 2 (active near the end of the tile range) ----------------
    if (t * 64 + 63 > R2) {
      f32x4 sc[4];
#pragma unroll
      for (int nt = 0; nt < 4; nt++) {
        int rr = nt * 16 + lc;
        bf16x8 kf0 = *(const bf16x8*)(Kl + rr * 64 + g0);
        bf16x8 kf1 = *(const bf16x8*)(Kl + rr * 64 + g1);
        f32x4 ss = zero4();
        ss = mfma16(kf0, qf2[0], ss);
        ss = mfma16(kf1, qf2[1], ss);
        sc[nt] = ss;
      }
      if (t * 64 <= R2 + 15) {
        int row = R2 + lc;
#pragma unroll
        for (int nt = 0; nt < 4; nt++)
#pragma unroll
          for (int r = 0; r < 4; r++) {
            int col = t * 64 + nt * 16 + quad * 4 + r;
            float pv = (col <= row) ? 0.0f : EXP2(sc[nt][r]);
            ls2 += pv;
            sc[nt][r] = pv;
          }
      } else {
#pragma unroll
        for (int nt = 0; nt < 4; nt++)
#pragma unroll
          for (int r = 0; r < 4; r++) {
            float pv = EXP2(sc[nt][r]);
            ls2 += pv;
            sc[nt][r] = pv;
          }
      }
#pragma unroll
      for (int nt = 0; nt < 4; nt++) {
        bf16x4 pk;
#pragma unroll
        for (int r = 0; r < 4; r++) pk[r] = (__bf16)sc[nt][r];
        *(bf16x4*)(plds + lc * 72 + nt * 16 + quad * 4) = pk;
      }
      __asm__ volatile("s_waitcnt lgkmcnt(0)" ::: "memory");
      bf16x8 pf0 = *(const bf16x8*)(plds + lc * 72 + quad * 8);
      bf16x8 pf1 = *(const bf16x8*)(plds + lc * 72 + 32 + quad * 8);
      __builtin_amdgcn_s_setprio(1);
#pragma unroll
      for (int ot = 0; ot < 4; ot++) {
        int rr = ot * 16 + lc;
        bf16x8 vf0 = *(const bf16x8*)(Vl + rr * 64 + g0);
        bf16x8 vf1 = *(const bf16x8*)(Vl + rr * 64 + g1);
        o2[ot] = mfma16(pf0, vf0, o2[ot]);
        o2[ot] = mfma16(pf1, vf1, o2[ot]);
      }
      __builtin_amdgcn_s_setprio(0);
    }
    __syncthreads();   // all waves done reading buf cb; next tile staged & visible
  }

  // ---- complete row-sums: combine the 4 quads holding partials for row lc ----
  ls1 += __shfl_xor(ls1, 16, 64);
  ls1 += __shfl_xor(ls1, 32, 64);
  ls2 += __shfl_xor(ls2, 16, 64);
  ls2 += __shfl_xor(ls2, 32, 64);
  // per-lane denominators for epilogue rows quad*4+r (broadcast from lane holding that row)
  float rl1[4], rl2[4];
#pragma unroll
  for (int r = 0; r < 4; r++) {
    rl1[r] = 1.0f / __shfl(ls1, quad * 4 + r, 64);
    rl2[r] = 1.0f / __shfl(ls2, quad * 4 + r, 64);
  }

  int b = bh >> 3, h = bh & 7;

  // ---- epilogue group 1: normalize into per-wave LDS tile, 16B coalesced stores ----
#pragma unroll
  for (int r = 0; r < 4; r++)
#pragma unroll
    for (int ot = 0; ot < 4; ot++)
      plds[(quad * 4 + r) * 72 + ot * 16 + lc] = (__bf16)(o1[ot][r] * rl1[r]);
  __asm__ volatile("s_waitcnt lgkmcnt(0)" ::: "memory");
#pragma unroll
  for (int it = 0; it < 2; it++) {
    int row = it * 8 + (lane >> 3);
    int c8 = (lane & 7) * 8;
    *(bf16x8*)(O + (b * S_ + R1 + row) * (H_ * A_) + h * 64 + c8) =
        *(const bf16x8*)(plds + row * 72 + c8);
  }

  // ---- epilogue group 2 (skip row 2047: NaN from 1/0; p==7 block rewrites it) ----
#pragma unroll
  for (int r = 0; r < 4; r++)
#pragma unroll
    for (int ot = 0; ot < 4; ot++)
      plds[(quad * 4 + r) * 72 + ot * 16 + lc] = (__bf16)(o2[ot][r] * rl2[r]);
  __asm__ volatile("s_waitcnt lgkmcnt(0)" ::: "memory");
#pragma unroll
  for (int it = 0; it < 2; it++) {
    int row = it * 8 + (lane >> 3);
    int c8 = (lane & 7) * 8;
    int grow = R2 + row;
    if (grow != S_ - 1)
      *(bf16x8*)(O + (b * S_ + grow) * (H_ * A_) + h * 64 + c8) =
          *(const bf16x8*)(plds + row * 72 + c8);
  }

  // ---- fused row-2047 fix: softmax over all -1e9 is uniform -> O = mean(V) ----
  if (p == 7) {
    int a = threadIdx.x >> 3;       // 0..63
    int li = threadIdx.x & 7;       // 8 lanes per a-row
    const __bf16* src = Vp + a * S_;
    float ssum = 0.f;
#pragma unroll 8
    for (int j2 = 0; j2 < 32; j2++) {
      bf16x8 vv = *(const bf16x8*)(src + (j2 * 8 + li) * 8);
#pragma unroll
      for (int e = 0; e < 8; e++) ssum += (float)vv[e];
    }
    ssum += __shfl_xor(ssum, 1, 64);
    ssum += __shfl_xor(ssum, 2, 64);
    ssum += __shfl_xor(ssum, 4, 64);
    if (li == 0)
      O[(b * S_ + (S_ - 1)) * (H_ * A_) + h * 64 + a] = (__bf16)(ssum * (1.0f / 2048.0f));
  }
}

// ---------------- output projection: [8192x512] @ [512x512] + bo, fp32 out ----------------
// Same LDS-staged BK=64 double-buffered main loop as proj_gemm; direct fp32 epilogue stores.
__global__ __launch_bounds__(256) void out_gemm_kernel(const __bf16* __restrict__ Ob,
                                                       const __bf16* __restrict__ Wot,
                                                       const float* __restrict__ bo,
                                                       float* __restrict__ out) {
  int lane = threadIdx.x & 63, wv = threadIdx.x >> 6;
  int wr = wv >> 1, wc = wv & 1;
  int quad = lane >> 4, lc = lane & 15;
  int M0 = blockIdx.x * 128, N0 = blockIdx.y * 128;
  int m0 = M0 + wr * 64, n0 = N0 + wc * 64;

  __shared__ __align__(16) __bf16 smem[2 * 2 * 128 * 64];

  int srow = lane >> 3;
  int sg = ((lane & 7) ^ srow) * 8;

#pragma unroll
  for (int i = 0; i < 4; ++i) {
    int r0 = wv * 32 + i * 8;
    GLDS(Ob  + (M0 + r0 + srow) * D_ + sg, AB(0) + r0 * 64);
    GLDS(Wot + (N0 + r0 + srow) * D_ + sg, BB(0) + r0 * 64);
  }

  f32x4 acc[4][4];
#pragma unroll
  for (int mt = 0; mt < 4; mt++)
#pragma unroll
    for (int nt = 0; nt < 4; nt++) acc[mt][nt] = zero4();

  __syncthreads();

  for (int j = 0; j < 8; ++j) {
    int cb = j & 1;
    if (j < 7) {
      int k0 = (j + 1) * 64;
#pragma unroll
      for (int i = 0; i < 4; ++i) {
        int r0 = wv * 32 + i * 8;
        GLDS(Ob  + (M0 + r0 + srow) * D_ + k0 + sg, AB(cb ^ 1) + r0 * 64);
        GLDS(Wot + (N0 + r0 + srow) * D_ + k0 + sg, BB(cb ^ 1) + r0 * 64);
      }
    }
    const __bf16* Al = AB(cb);
    const __bf16* Bl = BB(cb);
#pragma unroll
    for (int kk = 0; kk < 2; ++kk) {
      int gp = ((kk * 4 + quad) ^ (lc & 7)) * 8;
      bf16x8 a[4], bb[4];
#pragma unroll
      for (int mt = 0; mt < 4; mt++)
        a[mt] = *(const bf16x8*)(Al + (wr * 64 + mt * 16 + lc) * 64 + gp);
#pragma unroll
      for (int nt = 0; nt < 4; nt++)
        bb[nt] = *(const bf16x8*)(Bl + (wc * 64 + nt * 16 + lc) * 64 + gp);
#pragma unroll
      for (int mt = 0; mt < 4; mt++)
#pragma unroll
        for (int nt = 0; nt < 4; nt++)
          acc[mt][nt] = mfma16(a[mt], bb[nt], acc[mt][nt]);
    }
    __syncthreads();
  }

#pragma unroll
  for (int nt = 0; nt < 4; nt++) {
    int col = n0 + nt * 16 + lc;
    float bval = bo[col];
#pragma unroll
    for (int mt = 0; mt < 4; mt++)
#pragma unroll
      for (int r = 0; r < 4; r++) {
        int row = m0 + mt * 16 + quad * 4 + r;
        out[row * D_ + col] = acc[mt][nt][r] + bval;
      }
  }
}

extern "C" void kernel_launch(void* const* d_in, const int* in_sizes, int n_in,
                              void* d_out, int out_size, void* d_ws, size_t ws_size,
                              hipStream_t stream) {
  const float* q  = (const float*)d_in[0];
  const float* k  = (const float*)d_in[1];
  const float* v  = (const float*)d_in[2];
  const float* Wq = (const float*)d_in[3];
  const float* bq = (const float*)d_in[4];
  const float* Wk = (const float*)d_in[5];
  const float* bk = (const float*)d_in[6];
  const float* Wv = (const float*)d_in[7];
  const float* bv = (const float*)d_in[8];
  const float* Wo = (const float*)d_in[9];
  const float* bo = (const float*)d_in[10];

  char* ws = (char*)d_ws;
  __bf16* Xq  = (__bf16*)(ws + 0);          // 8 MiB each
  __bf16* Xk  = (__bf16*)(ws + 8388608);
  __bf16* Xv  = (__bf16*)(ws + 16777216);
  __bf16* Wtq = (__bf16*)(ws + 25165824);   // 512 KiB each
  __bf16* Wtk = (__bf16*)(ws + 25690112);
  __bf16* Wtv = (__bf16*)(ws + 26214400);
  __bf16* Wot = (__bf16*)(ws + 26738688);
  __bf16* Qb  = (__bf16*)(ws + 27262976);   // 8 MiB each
  __bf16* Kb  = (__bf16*)(ws + 35651584);
  __bf16* Vtb = (__bf16*)(ws + 44040192);
  __bf16* Ob  = (__bf16*)(ws + 52428800);

  prep_all_kernel<<<12544, 256, 0, stream>>>(q, k, v, Wq, Wk, Wv, Wo,
                                             Xq, Xk, Xv, Wtq, Wtk, Wtv, Wot);
  proj_gemm_kernel<<<dim3(64, 4, 3), 256, 0, stream>>>(Xq, Xk, Xv, Wtq, Wtk, Wtv,
                                                       bq, bk, bv, Qb, Kb, Vtb);
  flash_kernel<<<dim3(256), 512, 0, stream>>>(Qb, Kb, Vtb, Ob);
  out_gemm_kernel<<<dim3(64, 4), 256, 0, stream>>>(Ob, Wot, bo, (float*)d_out);
}